// Round 17
// baseline (1318.108 us; speedup 1.0000x reference)
//
#include <hip/hip_runtime.h>
#include <math.h>

typedef __attribute__((ext_vector_type(8))) short bf16x8;
typedef __attribute__((ext_vector_type(4))) float f32x4;

struct BN5 {
    const float* st[5];
    const float* g[5];
    const float* b[5];
    float invN;
};

static __device__ __forceinline__ short f2bf(float f) {
    unsigned u = __float_as_uint(f);
    unsigned r = (u + 0x7fffu + ((u >> 16) & 1u)) >> 16;
    return (short)r;
}
static __device__ __forceinline__ float bf2f(short s) {
    return __uint_as_float(((unsigned)(unsigned short)s) << 16);
}
static __device__ __forceinline__ float bflo(int v) { return bf2f((short)(v & 0xffff)); }
static __device__ __forceinline__ float bfhi(int v) { return bf2f((short)(((unsigned)v) >> 16)); }
static __device__ __forceinline__ int pack2(float a, float b) {
    return (int)(((unsigned)(unsigned short)f2bf(b) << 16) | (unsigned)(unsigned short)f2bf(a));
}

// ---------------- zero fill ----------------
__global__ void zero_i32_k(int* __restrict__ p, int n) {
    int i = blockIdx.x * 256 + threadIdx.x;
    if (i < n) p[i] = 0;
}

// ---------------- all weight converts+transposes in ONE launch ----------------
__global__ __launch_bounds__(256) void wconv_all_k(
    const float* __restrict__ emb, const float* __restrict__ gat,
    const float* __restrict__ ff1, const float* __restrict__ ff2,
    const float* __restrict__ dec,
    short* __restrict__ embT, short* __restrict__ gatT,
    short* __restrict__ ff1T, short* __restrict__ ff2T, short* __restrict__ decT)
{
    int gid = blockIdx.x * 256 + threadIdx.x;
    if (gid < 16384) {                        // emb_W2 [128][128]
        int k = gid >> 7, n = gid & 127;
        embT[n * 128 + k] = f2bf(emb[gid]);
    } else if (gid < 81920) {                 // gat_W [4][128][128]
        int local = gid - 16384;
        int sl = local >> 14, rem = local & 16383;
        int k = rem >> 7, n = rem & 127;
        gatT[sl * 16384 + n * 128 + k] = f2bf(gat[local]);
    } else if (gid < 212992) {                // ff_W1 [4][128][256]
        int local = gid - 81920;
        int sl = local >> 15, rem = local & 32767;
        int k = rem >> 8, n = rem & 255;
        ff1T[sl * 32768 + n * 128 + k] = f2bf(ff1[local]);
    } else if (gid < 344064) {                // ff_W2 [4][256][128]
        int local = gid - 212992;
        int sl = local >> 15, rem = local & 32767;
        int k = rem >> 7, n = rem & 127;
        ff2T[sl * 32768 + n * 256 + k] = f2bf(ff2[local]);
    } else if (gid < 425984) {                // dec_W1 [640][128]
        int local = gid - 344064;
        int k = local >> 7, n = local & 127;
        decT[n * 640 + k] = f2bf(dec[local]);
    }
}

// ---------------- embed ----------------
__global__ __launch_bounds__(256) void embed_k(
    const float* __restrict__ x, const float* __restrict__ W1, const float* __restrict__ b1,
    const float* __restrict__ Ws, const float* __restrict__ bs,
    int* __restrict__ u2, int* __restrict__ h2, int Nn)
{
    int idx = blockIdx.x * 256 + threadIdx.x;
    if (idx >= Nn * 64) return;
    int n = idx >> 6, c = (idx & 63) * 2;
    float x0 = x[2*n], x1 = x[2*n+1];
    float u0 = fmaxf(fmaf(x1, W1[128+c],   fmaf(x0, W1[c],   b1[c])),   0.f);
    float u1 = fmaxf(fmaf(x1, W1[128+c+1], fmaf(x0, W1[c+1], b1[c+1])), 0.f);
    float h0 = fmaf(x1, Ws[128+c],   fmaf(x0, Ws[c],   bs[c]));
    float h1 = fmaf(x1, Ws[128+c+1], fmaf(x0, Ws[c+1], bs[c+1]));
    u2[idx] = pack2(u0, u1);
    h2[idx] = pack2(h0, h1);
}

// ------- bf16 MFMA GEMM (B in LDS, A prefetch, BN fusion) -------
template<int NK, int RELU, int BETA, int ELR>
__global__ __launch_bounds__(256) void gemm2_k(
    const short* __restrict__ A0, const short* __restrict__ A1,
    const short* __restrict__ A2, const short* __restrict__ A3,
    const short* __restrict__ A4, int Astr,
    const short* __restrict__ Wt, int ldWt,
    const float* __restrict__ bias, short* __restrict__ C, const short* __restrict__ Rres,
    int Nrows, int ldC, BN5 bn,
    const float* __restrict__ al, const float* __restrict__ ar,
    float* __restrict__ elo, float* __restrict__ ero)
{
    __shared__ short Bs[128][136];
    const int row0 = blockIdx.x * 128;
    const int col0 = blockIdx.y * 128;
    const int t = threadIdx.x;
    const int w = t >> 6, lane = t & 63, q = lane >> 4, m = lane & 15;

    f32x4 acc[2][8];
    #pragma unroll
    for (int rb = 0; rb < 2; ++rb)
        #pragma unroll
        for (int cb = 0; cb < 8; ++cb)
            acc[rb][cb] = (f32x4){0.f, 0.f, 0.f, 0.f};

    const short* Asrc[5] = {A0, A1, A2, A3, A4};
    int rr0 = row0 + w*32 + m;      if (rr0 > Nrows - 1) rr0 = Nrows - 1;
    int rr1 = row0 + w*32 + 16 + m; if (rr1 > Nrows - 1) rr1 = Nrows - 1;

    #pragma unroll
    for (int kh = 0; kh < NK; ++kh) {
        if (kh) __syncthreads();
        #pragma unroll
        for (int it = 0; it < 8; ++it) {
            int ci = t + it * 256;
            int r = ci >> 4, j = (ci & 15) * 8;
            *(int4*)&Bs[r][j] = *(const int4*)(Wt + (size_t)(col0 + r) * ldWt + kh * 128 + j);
        }
        const short* pa0 = Asrc[kh] + (size_t)rr0 * Astr + q * 8;
        const short* pa1 = Asrc[kh] + (size_t)rr1 * Astr + q * 8;
        bf16x8 af0[4], af1[4];
        #pragma unroll
        for (int ks = 0; ks < 4; ++ks) {
            af0[ks] = *(const bf16x8*)(pa0 + ks * 32);
            af1[ks] = *(const bf16x8*)(pa1 + ks * 32);
        }
        if (bn.st[kh]) {
            const float* st = bn.st[kh];
            const float* gg = bn.g[kh];
            const float* bb = bn.b[kh];
            #pragma unroll
            for (int ks = 0; ks < 4; ++ks) {
                #pragma unroll
                for (int e = 0; e < 8; ++e) {
                    int c = ks * 32 + q * 8 + e;
                    float mu = st[c] * bn.invN;
                    float var = st[128 + c] * bn.invN - mu * mu;
                    float sc = rsqrtf(var + 1e-5f) * gg[c];
                    float bc = bb[c] - mu * sc;
                    af0[ks][e] = f2bf(fmaf(bf2f(af0[ks][e]), sc, bc));
                    af1[ks][e] = f2bf(fmaf(bf2f(af1[ks][e]), sc, bc));
                }
            }
        }
        __syncthreads();
        #pragma unroll
        for (int ks = 0; ks < 4; ++ks) {
            bf16x8 bfr[8];
            #pragma unroll
            for (int cb = 0; cb < 8; ++cb)
                bfr[cb] = *(const bf16x8*)&Bs[cb * 16 + m][ks * 32 + q * 8];
            #pragma unroll
            for (int cb = 0; cb < 8; ++cb) {
                acc[0][cb] = __builtin_amdgcn_mfma_f32_16x16x32_bf16(af0[ks], bfr[cb], acc[0][cb], 0, 0, 0);
                acc[1][cb] = __builtin_amdgcn_mfma_f32_16x16x32_bf16(af1[ks], bfr[cb], acc[1][cb], 0, 0, 0);
            }
        }
    }

    __syncthreads();
    short* Cs = (short*)Bs;
    #pragma unroll
    for (int rb = 0; rb < 2; ++rb) {
        #pragma unroll
        for (int r = 0; r < 4; ++r) {
            int lrow = w * 32 + rb * 16 + q * 4 + r;
            #pragma unroll
            for (int cb = 0; cb < 8; ++cb) {
                float v = acc[rb][cb][r];
                if (bias) v += bias[col0 + cb * 16 + m];
                if (RELU) v = fmaxf(v, 0.f);
                Cs[lrow * 132 + cb * 16 + m] = f2bf(v);
            }
        }
    }
    __syncthreads();
    const int chunk = t & 15, rgrp = t >> 4, cb8 = chunk * 8;
    const short* Rd = Rres ? Rres : C;
    #pragma unroll
    for (int j = 0; j < 8; ++j) {
        int r = rgrp + j * 16;
        int grow = row0 + r;
        if (grow < Nrows) {
            int2 u0 = *(const int2*)(Cs + r * 132 + cb8);
            int2 u1 = *(const int2*)(Cs + r * 132 + cb8 + 4);
            int4 cv = make_int4(u0.x, u0.y, u1.x, u1.y);
            size_t gb = (size_t)grow * ldC + col0 + cb8;
            if (BETA) {
                int4 rv = *(const int4*)(Rd + gb);
                int* cp = (int*)&cv; const int* rp = (const int*)&rv;
                #pragma unroll
                for (int e = 0; e < 4; ++e)
                    cp[e] = pack2(bflo(cp[e]) + bflo(rp[e]), bfhi(cp[e]) + bfhi(rp[e]));
            }
            *(int4*)(C + gb) = cv;
            if (ELR) {
                const int* cp = (const int*)&cv;
                float sl = 0.f, sr = 0.f;
                #pragma unroll
                for (int e = 0; e < 4; ++e) {
                    float lo = bflo(cp[e]), hi = bfhi(cp[e]);
                    sl = fmaf(lo, al[cb8 + 2*e], sl); sl = fmaf(hi, al[cb8 + 2*e + 1], sl);
                    sr = fmaf(lo, ar[cb8 + 2*e], sr); sr = fmaf(hi, ar[cb8 + 2*e + 1], sr);
                }
                elo[(size_t)grow * 16 + chunk] = sl;
                ero[(size_t)grow * 16 + chunk] = sr;
            }
        }
    }
}

// ------- fused FF block v3: sub-chunked W staging (51 KB LDS, VGPR<=170, 3 blocks/CU) -------
__global__ __launch_bounds__(256, 3) void ff_fused_k(
    const short* __restrict__ T1,
    const short* __restrict__ W1t,   // [256 cols][128 k]
    const short* __restrict__ W2t,   // [128 cols][256 k]
    const float* __restrict__ b1, const float* __restrict__ b2,
    const float* __restrict__ st1, const float* __restrict__ g1, const float* __restrict__ bb1,
    float invN, short* __restrict__ C, int Nrows, float* __restrict__ statsOut)
{
    __shared__ short Wbuf[9216];
    __shared__ short Fbuf[128 * 132];
    const int row0 = blockIdx.x * 128;
    const int t = threadIdx.x;
    const int w = t >> 6, lane = t & 63, q = lane >> 4, m = lane & 15;

    f32x4 acc2[2][8];
    #pragma unroll
    for (int rb = 0; rb < 2; ++rb)
        #pragma unroll
        for (int cb = 0; cb < 8; ++cb)
            acc2[rb][cb] = (f32x4){0.f, 0.f, 0.f, 0.f};

    int rr0 = row0 + w*32 + m;      if (rr0 > Nrows - 1) rr0 = Nrows - 1;
    int rr1 = row0 + w*32 + 16 + m; if (rr1 > Nrows - 1) rr1 = Nrows - 1;

    bf16x8 af0[4], af1[4];
    {
        const short* pa0 = T1 + (size_t)rr0 * 128 + q * 8;
        const short* pa1 = T1 + (size_t)rr1 * 128 + q * 8;
        #pragma unroll
        for (int ks = 0; ks < 4; ++ks) {
            af0[ks] = *(const bf16x8*)(pa0 + ks * 32);
            af1[ks] = *(const bf16x8*)(pa1 + ks * 32);
        }
        #pragma unroll
        for (int ks = 0; ks < 4; ++ks) {
            #pragma unroll
            for (int e = 0; e < 8; ++e) {
                int c = ks * 32 + q * 8 + e;
                float mu = st1[c] * invN;
                float var = st1[128 + c] * invN - mu * mu;
                float sc = rsqrtf(var + 1e-5f) * g1[c];
                float bc = bb1[c] - mu * sc;
                af0[ks][e] = f2bf(fmaf(bf2f(af0[ks][e]), sc, bc));
                af1[ks][e] = f2bf(fmaf(bf2f(af1[ks][e]), sc, bc));
            }
        }
    }

    for (int half = 0; half < 2; ++half) {
        for (int sub = 0; sub < 2; ++sub) {
            __syncthreads();
            #pragma unroll
            for (int it = 0; it < 4; ++it) {
                int ci = t + it * 256;
                int r = ci >> 4, j = (ci & 15) * 8;
                *(int4*)&Wbuf[r * 136 + j] =
                    *(const int4*)(W1t + (size_t)(half * 128 + sub * 64 + r) * 128 + j);
            }
            __syncthreads();
            f32x4 acc1[2][4];
            #pragma unroll
            for (int rb = 0; rb < 2; ++rb)
                #pragma unroll
                for (int cb = 0; cb < 4; ++cb)
                    acc1[rb][cb] = (f32x4){0.f, 0.f, 0.f, 0.f};
            #pragma unroll
            for (int ks = 0; ks < 4; ++ks) {
                bf16x8 bfr[4];
                #pragma unroll
                for (int cb = 0; cb < 4; ++cb)
                    bfr[cb] = *(const bf16x8*)&Wbuf[(cb * 16 + m) * 136 + ks * 32 + q * 8];
                #pragma unroll
                for (int cb = 0; cb < 4; ++cb) {
                    acc1[0][cb] = __builtin_amdgcn_mfma_f32_16x16x32_bf16(af0[ks], bfr[cb], acc1[0][cb], 0, 0, 0);
                    acc1[1][cb] = __builtin_amdgcn_mfma_f32_16x16x32_bf16(af1[ks], bfr[cb], acc1[1][cb], 0, 0, 0);
                }
            }
            #pragma unroll
            for (int rb = 0; rb < 2; ++rb) {
                #pragma unroll
                for (int r = 0; r < 4; ++r) {
                    int lrow = w * 32 + rb * 16 + q * 4 + r;
                    #pragma unroll
                    for (int cb = 0; cb < 4; ++cb) {
                        float v = acc1[rb][cb][r] + b1[half * 128 + sub * 64 + cb * 16 + m];
                        Fbuf[lrow * 132 + sub * 64 + cb * 16 + m] = f2bf(fmaxf(v, 0.f));
                    }
                }
            }
        }
        for (int sub = 0; sub < 2; ++sub) {
            __syncthreads();
            #pragma unroll
            for (int it = 0; it < 4; ++it) {
                int ci = t + it * 256;
                int r = ci >> 3, j = (ci & 7) * 8;
                *(int4*)&Wbuf[r * 72 + j] =
                    *(const int4*)(W2t + (size_t)r * 256 + half * 128 + sub * 64 + j);
            }
            __syncthreads();
            const short* fa0 = Fbuf + (w * 32 + m) * 132 + sub * 64 + q * 8;
            const short* fa1 = Fbuf + (w * 32 + 16 + m) * 132 + sub * 64 + q * 8;
            #pragma unroll
            for (int ks = 0; ks < 2; ++ks) {
                bf16x8 ga0 = *(const bf16x8*)(fa0 + ks * 32);
                bf16x8 ga1 = *(const bf16x8*)(fa1 + ks * 32);
                bf16x8 bfr[8];
                #pragma unroll
                for (int cb = 0; cb < 8; ++cb)
                    bfr[cb] = *(const bf16x8*)&Wbuf[(cb * 16 + m) * 72 + ks * 32 + q * 8];
                #pragma unroll
                for (int cb = 0; cb < 8; ++cb) {
                    acc2[0][cb] = __builtin_amdgcn_mfma_f32_16x16x32_bf16(ga0, bfr[cb], acc2[0][cb], 0, 0, 0);
                    acc2[1][cb] = __builtin_amdgcn_mfma_f32_16x16x32_bf16(ga1, bfr[cb], acc2[1][cb], 0, 0, 0);
                }
            }
        }
    }

    __syncthreads();
    #pragma unroll
    for (int rb = 0; rb < 2; ++rb) {
        #pragma unroll
        for (int r = 0; r < 4; ++r) {
            int lrow = w * 32 + rb * 16 + q * 4 + r;
            #pragma unroll
            for (int cb = 0; cb < 8; ++cb) {
                float v = acc2[rb][cb][r] + b2[cb * 16 + m];
                Fbuf[lrow * 132 + cb * 16 + m] = f2bf(v);
            }
        }
    }
    __syncthreads();
    const int chunk = t & 15, rgrp = t >> 4, cb8 = chunk * 8;
    float scR[8], bbR[8];
    #pragma unroll
    for (int e = 0; e < 8; ++e) {
        int c = cb8 + e;
        float mu = st1[c] * invN;
        float var = st1[128 + c] * invN - mu * mu;
        float sc = rsqrtf(var + 1e-5f) * g1[c];
        scR[e] = sc; bbR[e] = bb1[c] - mu * sc;
    }
    float sS[8], sQ[8];
    #pragma unroll
    for (int e = 0; e < 8; ++e) { sS[e] = 0.f; sQ[e] = 0.f; }
    #pragma unroll
    for (int j = 0; j < 8; ++j) {
        int r = rgrp + j * 16;
        int grow = row0 + r;
        if (grow < Nrows) {
            int2 u0 = *(const int2*)(Fbuf + r * 132 + cb8);
            int2 u1 = *(const int2*)(Fbuf + r * 132 + cb8 + 4);
            int4 cv = make_int4(u0.x, u0.y, u1.x, u1.y);
            size_t gb = (size_t)grow * 128 + cb8;
            int4 rv = *(const int4*)(T1 + gb);
            int* cp = (int*)&cv; const int* rp = (const int*)&rv;
            #pragma unroll
            for (int e = 0; e < 4; ++e) {
                float rlo = fmaf(bflo(rp[e]), scR[2*e],   bbR[2*e]);
                float rhi = fmaf(bfhi(rp[e]), scR[2*e+1], bbR[2*e+1]);
                float lo = bflo(cp[e]) + rlo;
                float hi = bfhi(cp[e]) + rhi;
                cp[e] = pack2(lo, hi);
                lo = bflo(cp[e]); hi = bfhi(cp[e]);
                sS[2*e]   += lo; sQ[2*e]   += lo * lo;
                sS[2*e+1] += hi; sQ[2*e+1] += hi * hi;
            }
            *(int4*)(C + gb) = cv;
        }
    }
    __syncthreads();
    float* fs = (float*)Wbuf;
    #pragma unroll
    for (int e = 0; e < 8; ++e) {
        fs[rgrp * 128 + cb8 + e]        = sS[e];
        fs[2048 + rgrp * 128 + cb8 + e] = sQ[e];
    }
    __syncthreads();
    if (t < 128) {
        float a = 0.f;
        #pragma unroll
        for (int g = 0; g < 16; ++g) a += fs[g * 128 + t];
        atomicAdd(&statsOut[t], a);
    } else {
        int c = t - 128;
        float a = 0.f;
        #pragma unroll
        for (int g = 0; g < 16; ++g) a += fs[2048 + g * 128 + c];
        atomicAdd(&statsOut[128 + c], a);
    }
}

// ---------------- CSR build ----------------
__global__ void count_k(const int* __restrict__ dst, int* __restrict__ cnt, int E) {
    int e = blockIdx.x * 256 + threadIdx.x;
    if (e < E) atomicAdd(&cnt[dst[e]], 1);
}

__global__ __launch_bounds__(256) void scan_part_k(const int* __restrict__ cnt,
                                                   int* __restrict__ bsum, int Nn) {
    __shared__ int red[256];
    int base = blockIdx.x * 1024;
    int s = 0;
    for (int i = threadIdx.x; i < 1024; i += 256) {
        int g = base + i;
        if (g < Nn) s += cnt[g];
    }
    red[threadIdx.x] = s; __syncthreads();
    for (int off = 128; off; off >>= 1) {
        if ((int)threadIdx.x < off) red[threadIdx.x] += red[threadIdx.x + off];
        __syncthreads();
    }
    if (threadIdx.x == 0) bsum[blockIdx.x] = red[0];
}

__global__ __launch_bounds__(256) void scan_top_k(int* __restrict__ bsum, int nb) {
    __shared__ int buf[256];
    int v = ((int)threadIdx.x < nb) ? bsum[threadIdx.x] : 0;
    buf[threadIdx.x] = v; __syncthreads();
    for (int off = 1; off < 256; off <<= 1) {
        int tv = ((int)threadIdx.x >= off) ? buf[threadIdx.x - off] : 0;
        __syncthreads();
        buf[threadIdx.x] += tv;
        __syncthreads();
    }
    if ((int)threadIdx.x < nb) bsum[threadIdx.x] = buf[threadIdx.x] - v;
}

__global__ __launch_bounds__(256) void scan_fin_k(const int* __restrict__ cnt,
    const int* __restrict__ bsum, int* __restrict__ rowptr, int* __restrict__ wpos, int Nn)
{
    __shared__ int tsum[256];
    int base = blockIdx.x * 1024;
    int g0 = base + (int)threadIdx.x * 4;
    int v[4]; int s = 0;
    #pragma unroll
    for (int j = 0; j < 4; ++j) {
        int g = g0 + j;
        v[j] = (g < Nn) ? cnt[g] : 0;
        s += v[j];
    }
    tsum[threadIdx.x] = s; __syncthreads();
    for (int off = 1; off < 256; off <<= 1) {
        int tv = ((int)threadIdx.x >= off) ? tsum[threadIdx.x - off] : 0;
        __syncthreads();
        tsum[threadIdx.x] += tv;
        __syncthreads();
    }
    int run = bsum[blockIdx.x] + tsum[threadIdx.x] - s;
    #pragma unroll
    for (int j = 0; j < 4; ++j) {
        int g = g0 + j;
        if (g < Nn) { wpos[g] = run; rowptr[g + 1] = run + v[j]; }
        run += v[j];
    }
    if (blockIdx.x == 0 && threadIdx.x == 0) rowptr[0] = 0;
}

__global__ void scatter_k(const int* __restrict__ src, const int* __restrict__ dst,
                          int* __restrict__ wpos, int* __restrict__ esrc, int E) {
    int e = blockIdx.x * 256 + threadIdx.x;
    if (e < E) {
        int p = atomicAdd(&wpos[dst[e]], 1);
        esrc[p] = src[e];
    }
}

// ------- GAT aggregate (h-BN fused) + fused BN stats of t1 -------
// 256 threads, 4 waves, 4 nodes per wave (16 nodes/block, 6250 blocks -> 25k waves).
__global__ __launch_bounds__(256) void gat_k(
    const short* __restrict__ h, const short* __restrict__ z,
    const float* __restrict__ el, const float* __restrict__ er,
    const int* __restrict__ rowptr, const int* __restrict__ esrc,
    const float* __restrict__ gbias, short* __restrict__ t1, int Nn,
    const float* __restrict__ hstats, const float* __restrict__ hg,
    const float* __restrict__ hb, float invN, float* __restrict__ statsOut)
{
    __shared__ float red[2][4][128];
    const int t = threadIdx.x;
    const int w = t >> 6, lane = t & 63;
    const int c = lane * 2;
    const int head = lane >> 2;

    float gb0 = gbias[c], gb1 = gbias[c+1];
    float hs0 = 1.f, hB0 = 0.f, hs1 = 1.f, hB1 = 0.f;
    if (hstats) {
        float mu0 = hstats[c] * invN;
        float v0  = hstats[128+c] * invN - mu0*mu0;
        hs0 = rsqrtf(v0 + 1e-5f) * hg[c];
        hB0 = hb[c] - mu0 * hs0;
        float mu1 = hstats[c+1] * invN;
        float v1  = hstats[128+c+1] * invN - mu1*mu1;
        hs1 = rsqrtf(v1 + 1e-5f) * hg[c+1];
        hB1 = hb[c+1] - mu1 * hs1;
    }

    float sS0 = 0.f, sS1 = 0.f, sQ0 = 0.f, sQ1 = 0.f;
    int base = blockIdx.x * 16;
    #pragma unroll
    for (int it = 0; it < 4; ++it) {
        int n = base + it * 4 + w;
        if (n >= Nn) break;
        float ern = er[n*16 + head];
        int beg = rowptr[n], end = rowptr[n+1];
        float m = -3.0e38f, den = 0.f, a0 = 0.f, a1 = 0.f;
        int i = beg;
        for (; i + 3 < end; i += 4) {
            int s0 = esrc[i], s1 = esrc[i+1], s2 = esrc[i+2], s3 = esrc[i+3];
            float e0 = el[s0*16 + head] + ern;
            float e1 = el[s1*16 + head] + ern;
            float e2 = el[s2*16 + head] + ern;
            float e3 = el[s3*16 + head] + ern;
            int zz0 = *(const int*)(z + (size_t)s0*128 + c);
            int zz1 = *(const int*)(z + (size_t)s1*128 + c);
            int zz2 = *(const int*)(z + (size_t)s2*128 + c);
            int zz3 = *(const int*)(z + (size_t)s3*128 + c);
            e0 = (e0 > 0.f) ? e0 : 0.2f * e0;
            e1 = (e1 > 0.f) ? e1 : 0.2f * e1;
            e2 = (e2 > 0.f) ? e2 : 0.2f * e2;
            e3 = (e3 > 0.f) ? e3 : 0.2f * e3;
            float nm = fmaxf(fmaxf(fmaxf(e0, e1), fmaxf(e2, e3)), m);
            float sc = __expf(m - nm);
            float w0 = __expf(e0 - nm), w1 = __expf(e1 - nm);
            float w2 = __expf(e2 - nm), w3 = __expf(e3 - nm);
            den = fmaf(den, sc, (w0 + w1) + (w2 + w3));
            a0 = fmaf(a0, sc, fmaf(w0, bflo(zz0), fmaf(w1, bflo(zz1), fmaf(w2, bflo(zz2), w3 * bflo(zz3)))));
            a1 = fmaf(a1, sc, fmaf(w0, bfhi(zz0), fmaf(w1, bfhi(zz1), fmaf(w2, bfhi(zz2), w3 * bfhi(zz3)))));
            m = nm;
        }
        for (; i + 1 < end; i += 2) {
            int s0 = esrc[i], s1 = esrc[i+1];
            float e0 = el[s0*16 + head] + ern;
            float e1 = el[s1*16 + head] + ern;
            int zz0 = *(const int*)(z + (size_t)s0*128 + c);
            int zz1 = *(const int*)(z + (size_t)s1*128 + c);
            e0 = (e0 > 0.f) ? e0 : 0.2f * e0;
            e1 = (e1 > 0.f) ? e1 : 0.2f * e1;
            float nm = fmaxf(m, fmaxf(e0, e1));
            float sc = __expf(m - nm);
            float w0 = __expf(e0 - nm);
            float w1 = __expf(e1 - nm);
            den = fmaf(den, sc, w0 + w1);
            a0  = fmaf(a0, sc, fmaf(w0, bflo(zz0), w1 * bflo(zz1)));
            a1  = fmaf(a1, sc, fmaf(w0, bfhi(zz0), w1 * bfhi(zz1)));
            m = nm;
        }
        if (i < end) {
            int s0 = esrc[i];
            float e0 = el[s0*16 + head] + ern;
            int zz0 = *(const int*)(z + (size_t)s0*128 + c);
            e0 = (e0 > 0.f) ? e0 : 0.2f * e0;
            float nm = fmaxf(m, e0);
            float sc = __expf(m - nm);
            float w0 = __expf(e0 - nm);
            den = fmaf(den, sc, w0);
            a0  = fmaf(a0, sc, w0 * bflo(zz0));
            a1  = fmaf(a1, sc, w0 * bfhi(zz0));
        }
        float inv = 1.f / den;
        size_t o = (size_t)n*64 + lane;
        int hv = ((const int*)h)[o];
        float r0 = fmaf(bflo(hv), hs0, hB0) + a0*inv + gb0;
        float r1 = fmaf(bfhi(hv), hs1, hB1) + a1*inv + gb1;
        int pk = pack2(r0, r1);
        ((int*)t1)[o] = pk;
        float v0 = bflo(pk), v1 = bfhi(pk);
        sS0 += v0; sQ0 = fmaf(v0, v0, sQ0);
        sS1 += v1; sQ1 = fmaf(v1, v1, sQ1);
    }
    red[0][w][c] = sS0; red[0][w][c+1] = sS1;
    red[1][w][c] = sQ0; red[1][w][c+1] = sQ1;
    __syncthreads();
    if (t < 128) {
        float a = red[0][0][t] + red[0][1][t] + red[0][2][t] + red[0][3][t];
        atomicAdd(&statsOut[t], a);
    } else {
        int cc = t - 128;
        float a = red[1][0][cc] + red[1][1][cc] + red[1][2][cc] + red[1][3][cc];
        atomicAdd(&statsOut[128 + cc], a);
    }
}

// ---------------- decoder output ----------------
__global__ __launch_bounds__(256) void dec_out_k(const short* __restrict__ udec,
    const float* __restrict__ W2, const float* __restrict__ b2,
    float* __restrict__ out, int Nn)
{
    int gw = (blockIdx.x * 256 + threadIdx.x) >> 6;
    if (gw >= Nn) return;
    int lane = threadIdx.x & 63;
    int v = ((const int*)(udec + (size_t)gw * 128))[lane];
    float p = bflo(v) * W2[lane*2] + bfhi(v) * W2[lane*2 + 1];
    #pragma unroll
    for (int off = 32; off > 0; off >>= 1) p += __shfl_down(p, off);
    if (lane == 0) out[gw] = p + b2[0];
}

extern "C" void kernel_launch(void* const* d_in, const int* in_sizes, int n_in,
                              void* d_out, int out_size, void* d_ws, size_t ws_size,
                              hipStream_t stream)
{
    const float* x      = (const float*)d_in[0];
    const int*   src    = (const int*)  d_in[1];
    const int*   dst    = (const int*)  d_in[2];
    const float* emb_W1 = (const float*)d_in[3];
    const float* emb_b1 = (const float*)d_in[4];
    const float* emb_W2 = (const float*)d_in[5];
    const float* emb_b2 = (const float*)d_in[6];
    const float* emb_Ws = (const float*)d_in[7];
    const float* emb_bs = (const float*)d_in[8];
    const float* gat_W  = (const float*)d_in[9];
    const float* gat_al = (const float*)d_in[10];
    const float* gat_ar = (const float*)d_in[11];
    const float* gat_b  = (const float*)d_in[12];
    const float* bn1_g  = (const float*)d_in[13];
    const float* bn1_b  = (const float*)d_in[14];
    const float* ff_W1  = (const float*)d_in[15];
    const float* ff_b1  = (const float*)d_in[16];
    const float* ff_W2  = (const float*)d_in[17];
    const float* ff_b2  = (const float*)d_in[18];
    const float* bn2_g  = (const float*)d_in[19];
    const float* bn2_b  = (const float*)d_in[20];
    const float* dec_W1 = (const float*)d_in[21];
    const float* dec_b1 = (const float*)d_in[22];
    const float* dec_W2 = (const float*)d_in[23];
    const float* dec_b2 = (const float*)d_in[24];
    float* out = (float*)d_out;
    (void)n_in; (void)out_size;

    const int N = in_sizes[0] / 2;
    const int E = in_sizes[1];
    const float invN = 1.f / (float)N;

    // ---- workspace ----
    char* p = (char*)d_ws;
    size_t used = 0;
    auto carve = [&](size_t bytes) {
        char* r = p; size_t a = (bytes + 255) & ~(size_t)255;
        p += a; used += a; return r;
    };
    const size_t nbH = (size_t)N * 128 * 2;
    short* xs[5];
    for (int i = 0; i < 5; ++i) xs[i] = (short*)carve(nbH);
    short* t1   = (short*)carve(nbH);
    char*  big  = (char*)carve(2 * nbH);
    int*   cnt    = (int*)carve((size_t)N * 4);
    float* stats8 = (float*)carve(8 * 256 * 4);
    int*   rowptr = (int*)carve((size_t)(N + 1) * 4);
    int*   wpos   = (int*)carve((size_t)N * 4);
    int*   esrc   = (int*)carve((size_t)E * 4);
    int*   bsum   = (int*)carve(256 * 4);
    short* emb_W2t = (short*)carve((size_t)128 * 128 * 2);
    short* gat_Wt  = (short*)carve((size_t)4 * 128 * 128 * 2);
    short* ff_W1t  = (short*)carve((size_t)4 * 128 * 256 * 2);
    short* ff_W2t  = (short*)carve((size_t)4 * 256 * 128 * 2);
    short* dec_W1t = (short*)carve((size_t)640 * 128 * 2);
    if (used > ws_size) return;

    short* u    = (short*)big;
    short* z    = (short*)big;
    float* el   = (float*)(big + nbH);
    float* er   = el + (size_t)N * 16;
    short* udec = (short*)big;

    dim3 b256(256);
    int ecb  = (E + 255) / 256;
    int nel2 = (N * 64 + 255) / 256;
    int gx   = (N + 127) / 128;
    int nwv  = (N + 3) / 4;
    int gblk = (N + 15) / 16;
    int nb   = (N + 1023) / 1024;

    BN5 bn0;
    for (int i = 0; i < 5; ++i) { bn0.st[i] = nullptr; bn0.g[i] = nullptr; bn0.b[i] = nullptr; }
    bn0.invN = invN;

    // ---- all weight converts in one launch ----
    wconv_all_k<<<(425984 + 255) / 256, b256, 0, stream>>>(
        emb_W2, gat_W, ff_W1, ff_W2, dec_W1,
        emb_W2t, gat_Wt, ff_W1t, ff_W2t, dec_W1t);

    // ---- zero cnt + 8 BN stats buffers ----
    {
        int ztot = (int)(((char*)(stats8 + 8*256) - (char*)cnt) / 4);
        zero_i32_k<<<(ztot + 255) / 256, b256, 0, stream>>>(cnt, ztot);
    }

    // ---- CSR build ----
    count_k<<<ecb, b256, 0, stream>>>(dst, cnt, E);
    scan_part_k<<<nb, b256, 0, stream>>>(cnt, bsum, N);
    scan_top_k<<<1, b256, 0, stream>>>(bsum, nb);
    scan_fin_k<<<nb, b256, 0, stream>>>(cnt, bsum, rowptr, wpos, N);
    scatter_k<<<ecb, b256, 0, stream>>>(src, dst, wpos, esrc, E);

    // ---- embed: xs0 = relu(x@W1+b1)@W2 + b2 + (x@Ws+bs) ----
    embed_k<<<nel2, b256, 0, stream>>>(x, emb_W1, emb_b1, emb_Ws, emb_bs, (int*)u, (int*)xs[0], N);
    gemm2_k<1,0,1,0><<<dim3(gx,1), b256, 0, stream>>>(u,u,u,u,u, 128, emb_W2t, 128,
        emb_b2, xs[0], nullptr, N, 128, bn0, nullptr, nullptr, nullptr, nullptr);

    for (int l = 0; l < 4; ++l) {
        float* st1 = stats8 + (size_t)(l*2)   * 256;
        float* st2 = stats8 + (size_t)(l*2+1) * 256;
        short* hl = xs[l];
        const float* hst = (l == 0) ? nullptr : stats8 + (size_t)((l-1)*2+1) * 256;
        const float* hgp = (l == 0) ? nullptr : bn2_g + (l-1)*128;
        const float* hbp = (l == 0) ? nullptr : bn2_b + (l-1)*128;

        // z = bn2(xs[l]) @ gatW[l]  (+ fused el/er)
        BN5 bz = bn0; bz.st[0] = hst; bz.g[0] = hgp; bz.b[0] = hbp;
        gemm2_k<1,0,0,1><<<dim3(gx,1), b256, 0, stream>>>(hl,hl,hl,hl,hl, 128,
            gat_Wt + (size_t)l*128*128, 128, nullptr, z, nullptr, N, 128, bz,
            gat_al + l*128, gat_ar + l*128, el, er);
        // GAT + fused stats(t1) -> st1
        gat_k<<<gblk, b256, 0, stream>>>(hl, z, el, er, rowptr, esrc, gat_b + l*128, t1, N,
                                         hst, hgp, hbp, invN, st1);
        // fused FF block: xs[l+1] = bn1(t1) + relu(bn1(t1)@W1+b1)@W2 + b2, stats -> st2
        ff_fused_k<<<gx, b256, 0, stream>>>(t1,
            ff_W1t + (size_t)l*128*256, ff_W2t + (size_t)l*256*128,
            ff_b1 + l*256, ff_b2 + l*128,
            st1, bn1_g + l*128, bn1_b + l*128, invN,
            xs[l+1], N, st2);
    }

    // ---- decoder: udec = relu(concat(xs0, bn2(t2_l)) @ dec_W1 + b1); out = udec.W2 + b2 ----
    BN5 bd = bn0;
    for (int k = 1; k < 5; ++k) {
        bd.st[k] = stats8 + (size_t)((k-1)*2+1) * 256;
        bd.g[k]  = bn2_g + (k-1)*128;
        bd.b[k]  = bn2_b + (k-1)*128;
    }
    gemm2_k<5,1,0,0><<<dim3(gx,1), b256, 0, stream>>>(xs[0], xs[1], xs[2], xs[3], xs[4], 128,
        dec_W1t, 640, dec_b1, udec, nullptr, N, 128, bd,
        nullptr, nullptr, nullptr, nullptr);
    dec_out_k<<<nwv, b256, 0, stream>>>(udec, dec_W2, dec_b2, out, N);
}

// Round 18
// 971.990 us; speedup vs baseline: 1.3561x; 1.3561x over previous
//
#include <hip/hip_runtime.h>
#include <math.h>

typedef __attribute__((ext_vector_type(8))) short bf16x8;
typedef __attribute__((ext_vector_type(4))) float f32x4;

struct BN5 {
    const float* st[5];
    const float* g[5];
    const float* b[5];
    float invN;
};

static __device__ __forceinline__ short f2bf(float f) {
    unsigned u = __float_as_uint(f);
    unsigned r = (u + 0x7fffu + ((u >> 16) & 1u)) >> 16;
    return (short)r;
}
static __device__ __forceinline__ float bf2f(short s) {
    return __uint_as_float(((unsigned)(unsigned short)s) << 16);
}
static __device__ __forceinline__ float bflo(int v) { return bf2f((short)(v & 0xffff)); }
static __device__ __forceinline__ float bfhi(int v) { return bf2f((short)(((unsigned)v) >> 16)); }
static __device__ __forceinline__ int pack2(float a, float b) {
    return (int)(((unsigned)(unsigned short)f2bf(b) << 16) | (unsigned)(unsigned short)f2bf(a));
}

// ---------------- zero fill ----------------
__global__ void zero_i32_k(int* __restrict__ p, int n) {
    int i = blockIdx.x * 256 + threadIdx.x;
    if (i < n) p[i] = 0;
}

// ---------------- all weight converts+transposes in ONE launch ----------------
__global__ __launch_bounds__(256) void wconv_all_k(
    const float* __restrict__ emb, const float* __restrict__ gat,
    const float* __restrict__ ff1, const float* __restrict__ ff2,
    const float* __restrict__ dec,
    short* __restrict__ embT, short* __restrict__ gatT,
    short* __restrict__ ff1T, short* __restrict__ ff2T, short* __restrict__ decT)
{
    int gid = blockIdx.x * 256 + threadIdx.x;
    if (gid < 16384) {                        // emb_W2 [128][128]
        int k = gid >> 7, n = gid & 127;
        embT[n * 128 + k] = f2bf(emb[gid]);
    } else if (gid < 81920) {                 // gat_W [4][128][128]
        int local = gid - 16384;
        int sl = local >> 14, rem = local & 16383;
        int k = rem >> 7, n = rem & 127;
        gatT[sl * 16384 + n * 128 + k] = f2bf(gat[local]);
    } else if (gid < 212992) {                // ff_W1 [4][128][256]
        int local = gid - 81920;
        int sl = local >> 15, rem = local & 32767;
        int k = rem >> 8, n = rem & 255;
        ff1T[sl * 32768 + n * 128 + k] = f2bf(ff1[local]);
    } else if (gid < 344064) {                // ff_W2 [4][256][128]
        int local = gid - 212992;
        int sl = local >> 15, rem = local & 32767;
        int k = rem >> 7, n = rem & 127;
        ff2T[sl * 32768 + n * 256 + k] = f2bf(ff2[local]);
    } else if (gid < 425984) {                // dec_W1 [640][128]
        int local = gid - 344064;
        int k = local >> 7, n = local & 127;
        decT[n * 640 + k] = f2bf(dec[local]);
    }
}

// ---------------- embed ----------------
__global__ __launch_bounds__(256) void embed_k(
    const float* __restrict__ x, const float* __restrict__ W1, const float* __restrict__ b1,
    const float* __restrict__ Ws, const float* __restrict__ bs,
    int* __restrict__ u2, int* __restrict__ h2, int Nn)
{
    int idx = blockIdx.x * 256 + threadIdx.x;
    if (idx >= Nn * 64) return;
    int n = idx >> 6, c = (idx & 63) * 2;
    float x0 = x[2*n], x1 = x[2*n+1];
    float u0 = fmaxf(fmaf(x1, W1[128+c],   fmaf(x0, W1[c],   b1[c])),   0.f);
    float u1 = fmaxf(fmaf(x1, W1[128+c+1], fmaf(x0, W1[c+1], b1[c+1])), 0.f);
    float h0 = fmaf(x1, Ws[128+c],   fmaf(x0, Ws[c],   bs[c]));
    float h1 = fmaf(x1, Ws[128+c+1], fmaf(x0, Ws[c+1], bs[c+1]));
    u2[idx] = pack2(u0, u1);
    h2[idx] = pack2(h0, h1);
}

// ------- bf16 MFMA GEMM (B in LDS, A prefetch, BN fusion) -------
template<int NK, int RELU, int BETA, int ELR>
__global__ __launch_bounds__(256) void gemm2_k(
    const short* __restrict__ A0, const short* __restrict__ A1,
    const short* __restrict__ A2, const short* __restrict__ A3,
    const short* __restrict__ A4, int Astr,
    const short* __restrict__ Wt, int ldWt,
    const float* __restrict__ bias, short* __restrict__ C, const short* __restrict__ Rres,
    int Nrows, int ldC, BN5 bn,
    const float* __restrict__ al, const float* __restrict__ ar,
    float* __restrict__ elo, float* __restrict__ ero)
{
    __shared__ short Bs[128][136];
    const int row0 = blockIdx.x * 128;
    const int col0 = blockIdx.y * 128;
    const int t = threadIdx.x;
    const int w = t >> 6, lane = t & 63, q = lane >> 4, m = lane & 15;

    f32x4 acc[2][8];
    #pragma unroll
    for (int rb = 0; rb < 2; ++rb)
        #pragma unroll
        for (int cb = 0; cb < 8; ++cb)
            acc[rb][cb] = (f32x4){0.f, 0.f, 0.f, 0.f};

    const short* Asrc[5] = {A0, A1, A2, A3, A4};
    int rr0 = row0 + w*32 + m;      if (rr0 > Nrows - 1) rr0 = Nrows - 1;
    int rr1 = row0 + w*32 + 16 + m; if (rr1 > Nrows - 1) rr1 = Nrows - 1;

    #pragma unroll
    for (int kh = 0; kh < NK; ++kh) {
        if (kh) __syncthreads();
        #pragma unroll
        for (int it = 0; it < 8; ++it) {
            int ci = t + it * 256;
            int r = ci >> 4, j = (ci & 15) * 8;
            *(int4*)&Bs[r][j] = *(const int4*)(Wt + (size_t)(col0 + r) * ldWt + kh * 128 + j);
        }
        const short* pa0 = Asrc[kh] + (size_t)rr0 * Astr + q * 8;
        const short* pa1 = Asrc[kh] + (size_t)rr1 * Astr + q * 8;
        bf16x8 af0[4], af1[4];
        #pragma unroll
        for (int ks = 0; ks < 4; ++ks) {
            af0[ks] = *(const bf16x8*)(pa0 + ks * 32);
            af1[ks] = *(const bf16x8*)(pa1 + ks * 32);
        }
        if (bn.st[kh]) {
            const float* st = bn.st[kh];
            const float* gg = bn.g[kh];
            const float* bb = bn.b[kh];
            #pragma unroll
            for (int ks = 0; ks < 4; ++ks) {
                #pragma unroll
                for (int e = 0; e < 8; ++e) {
                    int c = ks * 32 + q * 8 + e;
                    float mu = st[c] * bn.invN;
                    float var = st[128 + c] * bn.invN - mu * mu;
                    float sc = rsqrtf(var + 1e-5f) * gg[c];
                    float bc = bb[c] - mu * sc;
                    af0[ks][e] = f2bf(fmaf(bf2f(af0[ks][e]), sc, bc));
                    af1[ks][e] = f2bf(fmaf(bf2f(af1[ks][e]), sc, bc));
                }
            }
        }
        __syncthreads();
        #pragma unroll
        for (int ks = 0; ks < 4; ++ks) {
            bf16x8 bfr[8];
            #pragma unroll
            for (int cb = 0; cb < 8; ++cb)
                bfr[cb] = *(const bf16x8*)&Bs[cb * 16 + m][ks * 32 + q * 8];
            #pragma unroll
            for (int cb = 0; cb < 8; ++cb) {
                acc[0][cb] = __builtin_amdgcn_mfma_f32_16x16x32_bf16(af0[ks], bfr[cb], acc[0][cb], 0, 0, 0);
                acc[1][cb] = __builtin_amdgcn_mfma_f32_16x16x32_bf16(af1[ks], bfr[cb], acc[1][cb], 0, 0, 0);
            }
        }
    }

    __syncthreads();
    short* Cs = (short*)Bs;
    #pragma unroll
    for (int rb = 0; rb < 2; ++rb) {
        #pragma unroll
        for (int r = 0; r < 4; ++r) {
            int lrow = w * 32 + rb * 16 + q * 4 + r;
            #pragma unroll
            for (int cb = 0; cb < 8; ++cb) {
                float v = acc[rb][cb][r];
                if (bias) v += bias[col0 + cb * 16 + m];
                if (RELU) v = fmaxf(v, 0.f);
                Cs[lrow * 132 + cb * 16 + m] = f2bf(v);
            }
        }
    }
    __syncthreads();
    const int chunk = t & 15, rgrp = t >> 4, cb8 = chunk * 8;
    const short* Rd = Rres ? Rres : C;
    #pragma unroll
    for (int j = 0; j < 8; ++j) {
        int r = rgrp + j * 16;
        int grow = row0 + r;
        if (grow < Nrows) {
            int2 u0 = *(const int2*)(Cs + r * 132 + cb8);
            int2 u1 = *(const int2*)(Cs + r * 132 + cb8 + 4);
            int4 cv = make_int4(u0.x, u0.y, u1.x, u1.y);
            size_t gb = (size_t)grow * ldC + col0 + cb8;
            if (BETA) {
                int4 rv = *(const int4*)(Rd + gb);
                int* cp = (int*)&cv; const int* rp = (const int*)&rv;
                #pragma unroll
                for (int e = 0; e < 4; ++e)
                    cp[e] = pack2(bflo(cp[e]) + bflo(rp[e]), bfhi(cp[e]) + bfhi(rp[e]));
            }
            *(int4*)(C + gb) = cv;
            if (ELR) {
                const int* cp = (const int*)&cv;
                float sl = 0.f, sr = 0.f;
                #pragma unroll
                for (int e = 0; e < 4; ++e) {
                    float lo = bflo(cp[e]), hi = bfhi(cp[e]);
                    sl = fmaf(lo, al[cb8 + 2*e], sl); sl = fmaf(hi, al[cb8 + 2*e + 1], sl);
                    sr = fmaf(lo, ar[cb8 + 2*e], sr); sr = fmaf(hi, ar[cb8 + 2*e + 1], sr);
                }
                elo[(size_t)grow * 16 + chunk] = sl;
                ero[(size_t)grow * 16 + chunk] = sr;
            }
        }
    }
}

// ------- fused FF block v3: sub-chunked W staging (51 KB LDS, VGPR<=170, 3 blocks/CU) -------
__global__ __launch_bounds__(256, 3) void ff_fused_k(
    const short* __restrict__ T1,
    const short* __restrict__ W1t,   // [256 cols][128 k]
    const short* __restrict__ W2t,   // [128 cols][256 k]
    const float* __restrict__ b1, const float* __restrict__ b2,
    const float* __restrict__ st1, const float* __restrict__ g1, const float* __restrict__ bb1,
    float invN, short* __restrict__ C, int Nrows, float* __restrict__ statsOut)
{
    __shared__ short Wbuf[9216];
    __shared__ short Fbuf[128 * 132];
    const int row0 = blockIdx.x * 128;
    const int t = threadIdx.x;
    const int w = t >> 6, lane = t & 63, q = lane >> 4, m = lane & 15;

    f32x4 acc2[2][8];
    #pragma unroll
    for (int rb = 0; rb < 2; ++rb)
        #pragma unroll
        for (int cb = 0; cb < 8; ++cb)
            acc2[rb][cb] = (f32x4){0.f, 0.f, 0.f, 0.f};

    int rr0 = row0 + w*32 + m;      if (rr0 > Nrows - 1) rr0 = Nrows - 1;
    int rr1 = row0 + w*32 + 16 + m; if (rr1 > Nrows - 1) rr1 = Nrows - 1;

    bf16x8 af0[4], af1[4];
    {
        const short* pa0 = T1 + (size_t)rr0 * 128 + q * 8;
        const short* pa1 = T1 + (size_t)rr1 * 128 + q * 8;
        #pragma unroll
        for (int ks = 0; ks < 4; ++ks) {
            af0[ks] = *(const bf16x8*)(pa0 + ks * 32);
            af1[ks] = *(const bf16x8*)(pa1 + ks * 32);
        }
        #pragma unroll
        for (int ks = 0; ks < 4; ++ks) {
            #pragma unroll
            for (int e = 0; e < 8; ++e) {
                int c = ks * 32 + q * 8 + e;
                float mu = st1[c] * invN;
                float var = st1[128 + c] * invN - mu * mu;
                float sc = rsqrtf(var + 1e-5f) * g1[c];
                float bc = bb1[c] - mu * sc;
                af0[ks][e] = f2bf(fmaf(bf2f(af0[ks][e]), sc, bc));
                af1[ks][e] = f2bf(fmaf(bf2f(af1[ks][e]), sc, bc));
            }
        }
    }

    for (int half = 0; half < 2; ++half) {
        for (int sub = 0; sub < 2; ++sub) {
            __syncthreads();
            #pragma unroll
            for (int it = 0; it < 4; ++it) {
                int ci = t + it * 256;
                int r = ci >> 4, j = (ci & 15) * 8;
                *(int4*)&Wbuf[r * 136 + j] =
                    *(const int4*)(W1t + (size_t)(half * 128 + sub * 64 + r) * 128 + j);
            }
            __syncthreads();
            f32x4 acc1[2][4];
            #pragma unroll
            for (int rb = 0; rb < 2; ++rb)
                #pragma unroll
                for (int cb = 0; cb < 4; ++cb)
                    acc1[rb][cb] = (f32x4){0.f, 0.f, 0.f, 0.f};
            #pragma unroll
            for (int ks = 0; ks < 4; ++ks) {
                bf16x8 bfr[4];
                #pragma unroll
                for (int cb = 0; cb < 4; ++cb)
                    bfr[cb] = *(const bf16x8*)&Wbuf[(cb * 16 + m) * 136 + ks * 32 + q * 8];
                #pragma unroll
                for (int cb = 0; cb < 4; ++cb) {
                    acc1[0][cb] = __builtin_amdgcn_mfma_f32_16x16x32_bf16(af0[ks], bfr[cb], acc1[0][cb], 0, 0, 0);
                    acc1[1][cb] = __builtin_amdgcn_mfma_f32_16x16x32_bf16(af1[ks], bfr[cb], acc1[1][cb], 0, 0, 0);
                }
            }
            #pragma unroll
            for (int rb = 0; rb < 2; ++rb) {
                #pragma unroll
                for (int r = 0; r < 4; ++r) {
                    int lrow = w * 32 + rb * 16 + q * 4 + r;
                    #pragma unroll
                    for (int cb = 0; cb < 4; ++cb) {
                        float v = acc1[rb][cb][r] + b1[half * 128 + sub * 64 + cb * 16 + m];
                        Fbuf[lrow * 132 + sub * 64 + cb * 16 + m] = f2bf(fmaxf(v, 0.f));
                    }
                }
            }
        }
        for (int sub = 0; sub < 2; ++sub) {
            __syncthreads();
            #pragma unroll
            for (int it = 0; it < 4; ++it) {
                int ci = t + it * 256;
                int r = ci >> 3, j = (ci & 7) * 8;
                *(int4*)&Wbuf[r * 72 + j] =
                    *(const int4*)(W2t + (size_t)r * 256 + half * 128 + sub * 64 + j);
            }
            __syncthreads();
            const short* fa0 = Fbuf + (w * 32 + m) * 132 + sub * 64 + q * 8;
            const short* fa1 = Fbuf + (w * 32 + 16 + m) * 132 + sub * 64 + q * 8;
            #pragma unroll
            for (int ks = 0; ks < 2; ++ks) {
                bf16x8 ga0 = *(const bf16x8*)(fa0 + ks * 32);
                bf16x8 ga1 = *(const bf16x8*)(fa1 + ks * 32);
                bf16x8 bfr[8];
                #pragma unroll
                for (int cb = 0; cb < 8; ++cb)
                    bfr[cb] = *(const bf16x8*)&Wbuf[(cb * 16 + m) * 72 + ks * 32 + q * 8];
                #pragma unroll
                for (int cb = 0; cb < 8; ++cb) {
                    acc2[0][cb] = __builtin_amdgcn_mfma_f32_16x16x32_bf16(ga0, bfr[cb], acc2[0][cb], 0, 0, 0);
                    acc2[1][cb] = __builtin_amdgcn_mfma_f32_16x16x32_bf16(ga1, bfr[cb], acc2[1][cb], 0, 0, 0);
                }
            }
        }
    }

    __syncthreads();
    #pragma unroll
    for (int rb = 0; rb < 2; ++rb) {
        #pragma unroll
        for (int r = 0; r < 4; ++r) {
            int lrow = w * 32 + rb * 16 + q * 4 + r;
            #pragma unroll
            for (int cb = 0; cb < 8; ++cb) {
                float v = acc2[rb][cb][r] + b2[cb * 16 + m];
                Fbuf[lrow * 132 + cb * 16 + m] = f2bf(v);
            }
        }
    }
    __syncthreads();
    const int chunk = t & 15, rgrp = t >> 4, cb8 = chunk * 8;
    float scR[8], bbR[8];
    #pragma unroll
    for (int e = 0; e < 8; ++e) {
        int c = cb8 + e;
        float mu = st1[c] * invN;
        float var = st1[128 + c] * invN - mu * mu;
        float sc = rsqrtf(var + 1e-5f) * g1[c];
        scR[e] = sc; bbR[e] = bb1[c] - mu * sc;
    }
    float sS[8], sQ[8];
    #pragma unroll
    for (int e = 0; e < 8; ++e) { sS[e] = 0.f; sQ[e] = 0.f; }
    #pragma unroll
    for (int j = 0; j < 8; ++j) {
        int r = rgrp + j * 16;
        int grow = row0 + r;
        if (grow < Nrows) {
            int2 u0 = *(const int2*)(Fbuf + r * 132 + cb8);
            int2 u1 = *(const int2*)(Fbuf + r * 132 + cb8 + 4);
            int4 cv = make_int4(u0.x, u0.y, u1.x, u1.y);
            size_t gb = (size_t)grow * 128 + cb8;
            int4 rv = *(const int4*)(T1 + gb);
            int* cp = (int*)&cv; const int* rp = (const int*)&rv;
            #pragma unroll
            for (int e = 0; e < 4; ++e) {
                float rlo = fmaf(bflo(rp[e]), scR[2*e],   bbR[2*e]);
                float rhi = fmaf(bfhi(rp[e]), scR[2*e+1], bbR[2*e+1]);
                float lo = bflo(cp[e]) + rlo;
                float hi = bfhi(cp[e]) + rhi;
                cp[e] = pack2(lo, hi);
                lo = bflo(cp[e]); hi = bfhi(cp[e]);
                sS[2*e]   += lo; sQ[2*e]   += lo * lo;
                sS[2*e+1] += hi; sQ[2*e+1] += hi * hi;
            }
            *(int4*)(C + gb) = cv;
        }
    }
    __syncthreads();
    float* fs = (float*)Wbuf;
    #pragma unroll
    for (int e = 0; e < 8; ++e) {
        fs[rgrp * 128 + cb8 + e]        = sS[e];
        fs[2048 + rgrp * 128 + cb8 + e] = sQ[e];
    }
    __syncthreads();
    if (t < 128) {
        float a = 0.f;
        #pragma unroll
        for (int g = 0; g < 16; ++g) a += fs[g * 128 + t];
        atomicAdd(&statsOut[t], a);
    } else {
        int c = t - 128;
        float a = 0.f;
        #pragma unroll
        for (int g = 0; g < 16; ++g) a += fs[2048 + g * 128 + c];
        atomicAdd(&statsOut[128 + c], a);
    }
}

// ---------------- CSR build ----------------
__global__ void count_k(const int* __restrict__ dst, int* __restrict__ cnt, int E) {
    int e = blockIdx.x * 256 + threadIdx.x;
    if (e < E) atomicAdd(&cnt[dst[e]], 1);
}

__global__ __launch_bounds__(256) void scan_part_k(const int* __restrict__ cnt,
                                                   int* __restrict__ bsum, int Nn) {
    __shared__ int red[256];
    int base = blockIdx.x * 1024;
    int s = 0;
    for (int i = threadIdx.x; i < 1024; i += 256) {
        int g = base + i;
        if (g < Nn) s += cnt[g];
    }
    red[threadIdx.x] = s; __syncthreads();
    for (int off = 128; off; off >>= 1) {
        if ((int)threadIdx.x < off) red[threadIdx.x] += red[threadIdx.x + off];
        __syncthreads();
    }
    if (threadIdx.x == 0) bsum[blockIdx.x] = red[0];
}

__global__ __launch_bounds__(256) void scan_top_k(int* __restrict__ bsum, int nb) {
    __shared__ int buf[256];
    int v = ((int)threadIdx.x < nb) ? bsum[threadIdx.x] : 0;
    buf[threadIdx.x] = v; __syncthreads();
    for (int off = 1; off < 256; off <<= 1) {
        int tv = ((int)threadIdx.x >= off) ? buf[threadIdx.x - off] : 0;
        __syncthreads();
        buf[threadIdx.x] += tv;
        __syncthreads();
    }
    if ((int)threadIdx.x < nb) bsum[threadIdx.x] = buf[threadIdx.x] - v;
}

__global__ __launch_bounds__(256) void scan_fin_k(const int* __restrict__ cnt,
    const int* __restrict__ bsum, int* __restrict__ rowptr, int* __restrict__ wpos, int Nn)
{
    __shared__ int tsum[256];
    int base = blockIdx.x * 1024;
    int g0 = base + (int)threadIdx.x * 4;
    int v[4]; int s = 0;
    #pragma unroll
    for (int j = 0; j < 4; ++j) {
        int g = g0 + j;
        v[j] = (g < Nn) ? cnt[g] : 0;
        s += v[j];
    }
    tsum[threadIdx.x] = s; __syncthreads();
    for (int off = 1; off < 256; off <<= 1) {
        int tv = ((int)threadIdx.x >= off) ? tsum[threadIdx.x - off] : 0;
        __syncthreads();
        tsum[threadIdx.x] += tv;
        __syncthreads();
    }
    int run = bsum[blockIdx.x] + tsum[threadIdx.x] - s;
    #pragma unroll
    for (int j = 0; j < 4; ++j) {
        int g = g0 + j;
        if (g < Nn) { wpos[g] = run; rowptr[g + 1] = run + v[j]; }
        run += v[j];
    }
    if (blockIdx.x == 0 && threadIdx.x == 0) rowptr[0] = 0;
}

__global__ void scatter_k(const int* __restrict__ src, const int* __restrict__ dst,
                          int* __restrict__ wpos, int* __restrict__ esrc, int E) {
    int e = blockIdx.x * 256 + threadIdx.x;
    if (e < E) {
        int p = atomicAdd(&wpos[dst[e]], 1);
        esrc[p] = src[e];
    }
}

// ------- GAT aggregate (h-BN fused) + fused BN stats of t1 (64 nodes/block, measured best) -------
__global__ __launch_bounds__(256) void gat_k(
    const short* __restrict__ h, const short* __restrict__ z,
    const float* __restrict__ el, const float* __restrict__ er,
    const int* __restrict__ rowptr, const int* __restrict__ esrc,
    const float* __restrict__ gbias, short* __restrict__ t1, int Nn,
    const float* __restrict__ hstats, const float* __restrict__ hg,
    const float* __restrict__ hb, float invN, float* __restrict__ statsOut)
{
    __shared__ float red[2][4][128];
    const int t = threadIdx.x;
    const int w = t >> 6, lane = t & 63;
    const int c = lane * 2;
    const int head = lane >> 2;

    float gb0 = gbias[c], gb1 = gbias[c+1];
    float hs0 = 1.f, hB0 = 0.f, hs1 = 1.f, hB1 = 0.f;
    if (hstats) {
        float mu0 = hstats[c] * invN;
        float v0  = hstats[128+c] * invN - mu0*mu0;
        hs0 = rsqrtf(v0 + 1e-5f) * hg[c];
        hB0 = hb[c] - mu0 * hs0;
        float mu1 = hstats[c+1] * invN;
        float v1  = hstats[128+c+1] * invN - mu1*mu1;
        hs1 = rsqrtf(v1 + 1e-5f) * hg[c+1];
        hB1 = hb[c+1] - mu1 * hs1;
    }

    float sS0 = 0.f, sS1 = 0.f, sQ0 = 0.f, sQ1 = 0.f;
    int base = blockIdx.x * 64;
    for (int it = 0; it < 16; ++it) {
        int n = base + it * 4 + w;
        if (n >= Nn) break;
        float ern = er[n*16 + head];
        int beg = rowptr[n], end = rowptr[n+1];
        float m = -3.0e38f, den = 0.f, a0 = 0.f, a1 = 0.f;
        int i = beg;
        for (; i + 3 < end; i += 4) {
            int s0 = esrc[i], s1 = esrc[i+1], s2 = esrc[i+2], s3 = esrc[i+3];
            float e0 = el[s0*16 + head] + ern;
            float e1 = el[s1*16 + head] + ern;
            float e2 = el[s2*16 + head] + ern;
            float e3 = el[s3*16 + head] + ern;
            int zz0 = *(const int*)(z + (size_t)s0*128 + c);
            int zz1 = *(const int*)(z + (size_t)s1*128 + c);
            int zz2 = *(const int*)(z + (size_t)s2*128 + c);
            int zz3 = *(const int*)(z + (size_t)s3*128 + c);
            e0 = (e0 > 0.f) ? e0 : 0.2f * e0;
            e1 = (e1 > 0.f) ? e1 : 0.2f * e1;
            e2 = (e2 > 0.f) ? e2 : 0.2f * e2;
            e3 = (e3 > 0.f) ? e3 : 0.2f * e3;
            float nm = fmaxf(fmaxf(fmaxf(e0, e1), fmaxf(e2, e3)), m);
            float sc = __expf(m - nm);
            float w0 = __expf(e0 - nm), w1 = __expf(e1 - nm);
            float w2 = __expf(e2 - nm), w3 = __expf(e3 - nm);
            den = fmaf(den, sc, (w0 + w1) + (w2 + w3));
            a0 = fmaf(a0, sc, fmaf(w0, bflo(zz0), fmaf(w1, bflo(zz1), fmaf(w2, bflo(zz2), w3 * bflo(zz3)))));
            a1 = fmaf(a1, sc, fmaf(w0, bfhi(zz0), fmaf(w1, bfhi(zz1), fmaf(w2, bfhi(zz2), w3 * bfhi(zz3)))));
            m = nm;
        }
        for (; i + 1 < end; i += 2) {
            int s0 = esrc[i], s1 = esrc[i+1];
            float e0 = el[s0*16 + head] + ern;
            float e1 = el[s1*16 + head] + ern;
            int zz0 = *(const int*)(z + (size_t)s0*128 + c);
            int zz1 = *(const int*)(z + (size_t)s1*128 + c);
            e0 = (e0 > 0.f) ? e0 : 0.2f * e0;
            e1 = (e1 > 0.f) ? e1 : 0.2f * e1;
            float nm = fmaxf(m, fmaxf(e0, e1));
            float sc = __expf(m - nm);
            float w0 = __expf(e0 - nm);
            float w1 = __expf(e1 - nm);
            den = fmaf(den, sc, w0 + w1);
            a0  = fmaf(a0, sc, fmaf(w0, bflo(zz0), w1 * bflo(zz1)));
            a1  = fmaf(a1, sc, fmaf(w0, bfhi(zz0), w1 * bfhi(zz1)));
            m = nm;
        }
        if (i < end) {
            int s0 = esrc[i];
            float e0 = el[s0*16 + head] + ern;
            int zz0 = *(const int*)(z + (size_t)s0*128 + c);
            e0 = (e0 > 0.f) ? e0 : 0.2f * e0;
            float nm = fmaxf(m, e0);
            float sc = __expf(m - nm);
            float w0 = __expf(e0 - nm);
            den = fmaf(den, sc, w0);
            a0  = fmaf(a0, sc, w0 * bflo(zz0));
            a1  = fmaf(a1, sc, w0 * bfhi(zz0));
        }
        float inv = 1.f / den;
        size_t o = (size_t)n*64 + lane;
        int hv = ((const int*)h)[o];
        float r0 = fmaf(bflo(hv), hs0, hB0) + a0*inv + gb0;
        float r1 = fmaf(bfhi(hv), hs1, hB1) + a1*inv + gb1;
        int pk = pack2(r0, r1);
        ((int*)t1)[o] = pk;
        float v0 = bflo(pk), v1 = bfhi(pk);
        sS0 += v0; sQ0 = fmaf(v0, v0, sQ0);
        sS1 += v1; sQ1 = fmaf(v1, v1, sQ1);
    }
    red[0][w][c] = sS0; red[0][w][c+1] = sS1;
    red[1][w][c] = sQ0; red[1][w][c+1] = sQ1;
    __syncthreads();
    if (t < 128) {
        float a = red[0][0][t] + red[0][1][t] + red[0][2][t] + red[0][3][t];
        atomicAdd(&statsOut[t], a);
    } else {
        int cc = t - 128;
        float a = red[1][0][cc] + red[1][1][cc] + red[1][2][cc] + red[1][3][cc];
        atomicAdd(&statsOut[128 + cc], a);
    }
}

// ---------------- decoder output ----------------
__global__ __launch_bounds__(256) void dec_out_k(const short* __restrict__ udec,
    const float* __restrict__ W2, const float* __restrict__ b2,
    float* __restrict__ out, int Nn)
{
    int gw = (blockIdx.x * 256 + threadIdx.x) >> 6;
    if (gw >= Nn) return;
    int lane = threadIdx.x & 63;
    int v = ((const int*)(udec + (size_t)gw * 128))[lane];
    float p = bflo(v) * W2[lane*2] + bfhi(v) * W2[lane*2 + 1];
    #pragma unroll
    for (int off = 32; off > 0; off >>= 1) p += __shfl_down(p, off);
    if (lane == 0) out[gw] = p + b2[0];
}

extern "C" void kernel_launch(void* const* d_in, const int* in_sizes, int n_in,
                              void* d_out, int out_size, void* d_ws, size_t ws_size,
                              hipStream_t stream)
{
    const float* x      = (const float*)d_in[0];
    const int*   src    = (const int*)  d_in[1];
    const int*   dst    = (const int*)  d_in[2];
    const float* emb_W1 = (const float*)d_in[3];
    const float* emb_b1 = (const float*)d_in[4];
    const float* emb_W2 = (const float*)d_in[5];
    const float* emb_b2 = (const float*)d_in[6];
    const float* emb_Ws = (const float*)d_in[7];
    const float* emb_bs = (const float*)d_in[8];
    const float* gat_W  = (const float*)d_in[9];
    const float* gat_al = (const float*)d_in[10];
    const float* gat_ar = (const float*)d_in[11];
    const float* gat_b  = (const float*)d_in[12];
    const float* bn1_g  = (const float*)d_in[13];
    const float* bn1_b  = (const float*)d_in[14];
    const float* ff_W1  = (const float*)d_in[15];
    const float* ff_b1  = (const float*)d_in[16];
    const float* ff_W2  = (const float*)d_in[17];
    const float* ff_b2  = (const float*)d_in[18];
    const float* bn2_g  = (const float*)d_in[19];
    const float* bn2_b  = (const float*)d_in[20];
    const float* dec_W1 = (const float*)d_in[21];
    const float* dec_b1 = (const float*)d_in[22];
    const float* dec_W2 = (const float*)d_in[23];
    const float* dec_b2 = (const float*)d_in[24];
    float* out = (float*)d_out;
    (void)n_in; (void)out_size;

    const int N = in_sizes[0] / 2;
    const int E = in_sizes[1];
    const float invN = 1.f / (float)N;

    // ---- workspace ----
    char* p = (char*)d_ws;
    size_t used = 0;
    auto carve = [&](size_t bytes) {
        char* r = p; size_t a = (bytes + 255) & ~(size_t)255;
        p += a; used += a; return r;
    };
    const size_t nbH = (size_t)N * 128 * 2;
    short* xs[5];
    for (int i = 0; i < 5; ++i) xs[i] = (short*)carve(nbH);
    short* t1   = (short*)carve(nbH);
    char*  big  = (char*)carve(2 * nbH);
    int*   cnt    = (int*)carve((size_t)N * 4);
    float* stats8 = (float*)carve(8 * 256 * 4);
    int*   rowptr = (int*)carve((size_t)(N + 1) * 4);
    int*   wpos   = (int*)carve((size_t)N * 4);
    int*   esrc   = (int*)carve((size_t)E * 4);
    int*   bsum   = (int*)carve(256 * 4);
    short* emb_W2t = (short*)carve((size_t)128 * 128 * 2);
    short* gat_Wt  = (short*)carve((size_t)4 * 128 * 128 * 2);
    short* ff_W1t  = (short*)carve((size_t)4 * 128 * 256 * 2);
    short* ff_W2t  = (short*)carve((size_t)4 * 256 * 128 * 2);
    short* dec_W1t = (short*)carve((size_t)640 * 128 * 2);
    if (used > ws_size) return;

    short* u    = (short*)big;
    short* z    = (short*)big;
    float* el   = (float*)(big + nbH);
    float* er   = el + (size_t)N * 16;
    short* udec = (short*)big;

    dim3 b256(256);
    int ecb  = (E + 255) / 256;
    int nel2 = (N * 64 + 255) / 256;
    int gx   = (N + 127) / 128;
    int nwv  = (N + 3) / 4;
    int gblk = (N + 63) / 64;
    int nb   = (N + 1023) / 1024;

    BN5 bn0;
    for (int i = 0; i < 5; ++i) { bn0.st[i] = nullptr; bn0.g[i] = nullptr; bn0.b[i] = nullptr; }
    bn0.invN = invN;

    // ---- all weight converts in one launch ----
    wconv_all_k<<<(425984 + 255) / 256, b256, 0, stream>>>(
        emb_W2, gat_W, ff_W1, ff_W2, dec_W1,
        emb_W2t, gat_Wt, ff_W1t, ff_W2t, dec_W1t);

    // ---- zero cnt + 8 BN stats buffers ----
    {
        int ztot = (int)(((char*)(stats8 + 8*256) - (char*)cnt) / 4);
        zero_i32_k<<<(ztot + 255) / 256, b256, 0, stream>>>(cnt, ztot);
    }

    // ---- CSR build ----
    count_k<<<ecb, b256, 0, stream>>>(dst, cnt, E);
    scan_part_k<<<nb, b256, 0, stream>>>(cnt, bsum, N);
    scan_top_k<<<1, b256, 0, stream>>>(bsum, nb);
    scan_fin_k<<<nb, b256, 0, stream>>>(cnt, bsum, rowptr, wpos, N);
    scatter_k<<<ecb, b256, 0, stream>>>(src, dst, wpos, esrc, E);

    // ---- embed: xs0 = relu(x@W1+b1)@W2 + b2 + (x@Ws+bs) ----
    embed_k<<<nel2, b256, 0, stream>>>(x, emb_W1, emb_b1, emb_Ws, emb_bs, (int*)u, (int*)xs[0], N);
    gemm2_k<1,0,1,0><<<dim3(gx,1), b256, 0, stream>>>(u,u,u,u,u, 128, emb_W2t, 128,
        emb_b2, xs[0], nullptr, N, 128, bn0, nullptr, nullptr, nullptr, nullptr);

    for (int l = 0; l < 4; ++l) {
        float* st1 = stats8 + (size_t)(l*2)   * 256;
        float* st2 = stats8 + (size_t)(l*2+1) * 256;
        short* hl = xs[l];
        const float* hst = (l == 0) ? nullptr : stats8 + (size_t)((l-1)*2+1) * 256;
        const float* hgp = (l == 0) ? nullptr : bn2_g + (l-1)*128;
        const float* hbp = (l == 0) ? nullptr : bn2_b + (l-1)*128;

        // z = bn2(xs[l]) @ gatW[l]  (+ fused el/er)
        BN5 bz = bn0; bz.st[0] = hst; bz.g[0] = hgp; bz.b[0] = hbp;
        gemm2_k<1,0,0,1><<<dim3(gx,1), b256, 0, stream>>>(hl,hl,hl,hl,hl, 128,
            gat_Wt + (size_t)l*128*128, 128, nullptr, z, nullptr, N, 128, bz,
            gat_al + l*128, gat_ar + l*128, el, er);
        // GAT + fused stats(t1) -> st1
        gat_k<<<gblk, b256, 0, stream>>>(hl, z, el, er, rowptr, esrc, gat_b + l*128, t1, N,
                                         hst, hgp, hbp, invN, st1);
        // fused FF block: xs[l+1] = bn1(t1) + relu(bn1(t1)@W1+b1)@W2 + b2, stats -> st2
        ff_fused_k<<<gx, b256, 0, stream>>>(t1,
            ff_W1t + (size_t)l*128*256, ff_W2t + (size_t)l*256*128,
            ff_b1 + l*256, ff_b2 + l*128,
            st1, bn1_g + l*128, bn1_b + l*128, invN,
            xs[l+1], N, st2);
    }

    // ---- decoder: udec = relu(concat(xs0, bn2(t2_l)) @ dec_W1 + b1); out = udec.W2 + b2 ----
    BN5 bd = bn0;
    for (int k = 1; k < 5; ++k) {
        bd.st[k] = stats8 + (size_t)((k-1)*2+1) * 256;
        bd.g[k]  = bn2_g + (k-1)*128;
        bd.b[k]  = bn2_b + (k-1)*128;
    }
    gemm2_k<5,1,0,0><<<dim3(gx,1), b256, 0, stream>>>(xs[0], xs[1], xs[2], xs[3], xs[4], 128,
        dec_W1t, 640, dec_b1, udec, nullptr, N, 128, bd,
        nullptr, nullptr, nullptr, nullptr);
    dec_out_k<<<nwv, b256, 0, stream>>>(udec, dec_W2, dec_b2, out, N);
}